// Round 4
// baseline (244.467 us; speedup 1.0000x reference)
//
#include <hip/hip_runtime.h>
#include <cstdint>
#include <cstddef>

// ---------------------------------------------------------------------------
// Pre-LN multi-head attention block. B=4, N=2048, D=768, H=12, Dh=64.
// bf16 MFMA 16x16x32; fp32 in/out. XOR-swizzled LDS tiles; S^T trick:
// compute K·Q^T so each lane holds 4 consecutive keys -> b64 packed P writes.
// ---------------------------------------------------------------------------

#define SEQ    2048
#define NBATCH 4
#define DMODEL 768
#define NHEADS 12
#define DHEAD  64
#define MROWS  (NBATCH * SEQ)   // 8192
#define NQKV   (3 * DMODEL)     // 2304
#define KT     64               // attention key-tile
#define NT     (SEQ / KT)       // 32

using f32x4  = __attribute__((ext_vector_type(4))) float;
using u16x8  = __attribute__((ext_vector_type(8))) unsigned short;
using s16x8  = __attribute__((ext_vector_type(8))) short;

__device__ __forceinline__ unsigned short f2bf(float f) {
  union { float f; unsigned int u; } x; x.f = f;
  unsigned int r = x.u + 0x7fffu + ((x.u >> 16) & 1u);   // RNE
  return (unsigned short)(r >> 16);
}

// packed f32x2 -> bf16x2 (low = a). HW on gfx950, SW fallback otherwise.
#if defined(__has_builtin)
#if __has_builtin(__builtin_amdgcn_cvt_pk_bf16_f32)
#define HAVE_PK_BF16 1
#endif
#endif
__device__ __forceinline__ unsigned int pk_bf16(float a, float b) {
#ifdef HAVE_PK_BF16
  auto v = __builtin_amdgcn_cvt_pk_bf16_f32(a, b);
  union { decltype(v) v2; unsigned int u; } c; c.v2 = v; return c.u;
#else
  return (unsigned int)f2bf(a) | ((unsigned int)f2bf(b) << 16);
#endif
}

__device__ __forceinline__ f32x4 mfma16(u16x8 a, u16x8 b, f32x4 c) {
  return __builtin_amdgcn_mfma_f32_16x16x32_bf16((s16x8)a, (s16x8)b, c, 0, 0, 0);
}

// async global->LDS, 16B/lane; lane i writes LDS base + i*16
__device__ __forceinline__ void gl_lds16(const void* g, void* l) {
  __builtin_amdgcn_global_load_lds(
      (const __attribute__((address_space(1))) void*)g,
      (__attribute__((address_space(3))) void*)l, 16, 0, 0);
}

// ---------------------------------------------------------------------------
// LayerNorm: fp32 x[8192][768] -> bf16 xn[8192][768]
// ---------------------------------------------------------------------------
__global__ __launch_bounds__(256) void ln_kernel(
    const float* __restrict__ x, const float* __restrict__ g,
    const float* __restrict__ bb, unsigned short* __restrict__ xn) {
  __shared__ float red[8];
  const int row = blockIdx.x, t = threadIdx.x;
  const float* xr = x + (size_t)row * DMODEL;
  float v0 = xr[t], v1 = xr[t + 256], v2 = xr[t + 512];
  float s = v0 + v1 + v2;
#pragma unroll
  for (int o = 32; o; o >>= 1) s += __shfl_down(s, o);
  if ((t & 63) == 0) red[t >> 6] = s;
  __syncthreads();
  float mu = (red[0] + red[1] + red[2] + red[3]) * (1.0f / DMODEL);
  float d0 = v0 - mu, d1 = v1 - mu, d2 = v2 - mu;
  float q = d0 * d0 + d1 * d1 + d2 * d2;
#pragma unroll
  for (int o = 32; o; o >>= 1) q += __shfl_down(q, o);
  if ((t & 63) == 0) red[4 + (t >> 6)] = q;
  __syncthreads();
  float var = (red[4] + red[5] + red[6] + red[7]) * (1.0f / DMODEL);
  float rstd = rsqrtf(var + 1e-5f);
  size_t base = (size_t)row * DMODEL;
  xn[base + t]       = f2bf(d0 * rstd * g[t]       + bb[t]);
  xn[base + t + 256] = f2bf(d1 * rstd * g[t + 256] + bb[t + 256]);
  xn[base + t + 512] = f2bf(d2 * rstd * g[t + 512] + bb[t + 512]);
}

// ---------------------------------------------------------------------------
// Transpose + fp32->bf16: W[K=768][N] -> Wt[N][768]
// ---------------------------------------------------------------------------
__global__ __launch_bounds__(256) void tconv_kernel(
    const float* __restrict__ W, unsigned short* __restrict__ Wt, int N) {
  __shared__ float tile[32][33];
  const int n0 = blockIdx.x * 32, k0 = blockIdx.y * 32;
  const int tx = threadIdx.x & 31, ty = threadIdx.x >> 5;
#pragma unroll
  for (int r = 0; r < 4; ++r)
    tile[ty + r * 8][tx] = W[(size_t)(k0 + ty + r * 8) * N + n0 + tx];
  __syncthreads();
#pragma unroll
  for (int r = 0; r < 4; ++r)
    Wt[(size_t)(n0 + ty + r * 8) * DMODEL + k0 + tx] = f2bf(tile[tx][ty + r * 8]);
}

// ---------------------------------------------------------------------------
// GEMM1: xn @ W_qkv + b_qkv. BK=64, swizzled LDS.
// q [bh][n][64] scaled 1/8; k [bh][n][64]; v -> vt [bh][d][SEQ] packed b64.
// ---------------------------------------------------------------------------
__global__ __launch_bounds__(256, 3) void gemm_qkv_kernel(
    const unsigned short* __restrict__ A, const unsigned short* __restrict__ Bt,
    const float* __restrict__ bias, unsigned short* __restrict__ qb,
    unsigned short* __restrict__ kb, unsigned short* __restrict__ vt) {
  __shared__ alignas(16) unsigned short As[128 * 64];
  __shared__ alignas(16) unsigned short Bs[128 * 64];
  const int t = threadIdx.x, wid = t >> 6, l = t & 63, quad = l >> 4, ll = l & 15;
  const int m0 = blockIdx.x * 128, n0 = blockIdx.y * 128;
  const int wm = (wid >> 1) * 64, wn = (wid & 1) * 64;
  const int srow = l >> 3;                    // 0..7 within a staging call
  const int sblk = (l & 7) ^ srow;            // swizzled 16B-block in source
  f32x4 acc[4][4] = {};
  for (int k0 = 0; k0 < DMODEL; k0 += 64) {
#pragma unroll
    for (int cc = 0; cc < 4; ++cc) {
      int call = wid * 4 + cc;                 // 16 calls cover 128 rows
      int r = call * 8 + srow;
      gl_lds16(A  + (size_t)(m0 + r) * DMODEL + k0 + sblk * 8, &As[call * 512]);
      gl_lds16(Bt + (size_t)(n0 + r) * DMODEL + k0 + sblk * 8, &Bs[call * 512]);
    }
    __syncthreads();
#pragma unroll
    for (int ks = 0; ks < 2; ++ks) {
      u16x8 af[4], bf[4];
#pragma unroll
      for (int i = 0; i < 4; ++i) {
        int ra = wm + i * 16 + ll, rb = wn + i * 16 + ll;
        int blk = (ks * 4 + quad) ^ (ll & 7);
        af[i] = *(const u16x8*)&As[ra * 64 + blk * 8];
        bf[i] = *(const u16x8*)&Bs[rb * 64 + blk * 8];
      }
#pragma unroll
      for (int mi = 0; mi < 4; ++mi)
#pragma unroll
        for (int ni = 0; ni < 4; ++ni)
          acc[mi][ni] = mfma16(af[mi], bf[ni], acc[mi][ni]);
    }
    __syncthreads();
  }
  const int which = (n0 >= 2 * DMODEL) ? 2 : (n0 >= DMODEL ? 1 : 0);  // block-uniform
#pragma unroll
  for (int mi = 0; mi < 4; ++mi) {
    int gm = m0 + wm + mi * 16 + quad * 4;
    int b = gm >> 11, i0 = gm & 2047;
#pragma unroll
    for (int ni = 0; ni < 4; ++ni) {
      int gn = n0 + wn + ni * 16 + ll;
      float bv = bias[gn];
      int rem = gn - which * DMODEL;
      int h = rem >> 6, d = rem & 63;
      int bh = b * NHEADS + h;
      if (which == 0) {
#pragma unroll
        for (int r = 0; r < 4; ++r)
          qb[(size_t)(bh * SEQ + i0 + r) * DHEAD + d] = f2bf((acc[mi][ni][r] + bv) * 0.125f);
      } else if (which == 1) {
#pragma unroll
        for (int r = 0; r < 4; ++r)
          kb[(size_t)(bh * SEQ + i0 + r) * DHEAD + d] = f2bf(acc[mi][ni][r] + bv);
      } else {
        uint2 pk;
        pk.x = pk_bf16(acc[mi][ni][0] + bv, acc[mi][ni][1] + bv);
        pk.y = pk_bf16(acc[mi][ni][2] + bv, acc[mi][ni][3] + bv);
        *(uint2*)&vt[((size_t)bh * DHEAD + d) * SEQ + i0] = pk;
      }
    }
  }
}

// ---------------------------------------------------------------------------
// Flash attention, streaming sum-of-exp (no online max; s is O(1) scaled).
// grid (16 q-tiles, 48 bh), block 256 (4 waves x 32 q-rows).
// S^T = K·Q^T: lane holds qrow=ll, keys quad*4+r -> packed b64 P writes.
// K-tile 64, double-buffered DMA staging, one barrier/iter, swizzled tiles.
// ---------------------------------------------------------------------------
__global__ __launch_bounds__(256, 3) void attn_kernel(
    const unsigned short* __restrict__ qbuf, const unsigned short* __restrict__ kbuf,
    const unsigned short* __restrict__ vtg, unsigned short* __restrict__ ao) {
  __shared__ alignas(16) unsigned short stage[2][2][KT * DHEAD]; // [buf][K,Vt]
  __shared__ alignas(16) unsigned short Pws[4][32 * 72];
  const int t = threadIdx.x, wid = t >> 6, l = t & 63, quad = l >> 4, ll = l & 15;
  const int qt = blockIdx.x, bh = blockIdx.y;
  const unsigned short* qg  = qbuf + ((size_t)bh * SEQ + qt * 128) * DHEAD;
  const unsigned short* kg0 = kbuf + (size_t)bh * SEQ * DHEAD;
  const unsigned short* vt0 = vtg  + (size_t)bh * DHEAD * SEQ;
  const int srow = l >> 3;                    // 0..7
  const int sblk = (l & 7) ^ srow;            // swizzled source block

  // stage Q (16KB over stage[0], swizzled), hoist fragments, free region
  unsigned short* Qs = &stage[0][0][0];
#pragma unroll
  for (int cc = 0; cc < 4; ++cc) {
    int call = wid * 4 + cc;                  // 16 calls x 8 rows = 128 rows
    gl_lds16(qg + (call * 8 + srow) * 64 + sblk * 8, Qs + call * 512);
  }
  __syncthreads();
  u16x8 qf[2][2];
#pragma unroll
  for (int mi = 0; mi < 2; ++mi)
#pragma unroll
    for (int ks = 0; ks < 2; ++ks) {
      int r = wid * 32 + mi * 16 + ll;
      int blk = (ks * 4 + quad) ^ (ll & 7);
      qf[mi][ks] = *(const u16x8*)&Qs[r * 64 + blk * 8];
    }
  __syncthreads();

  auto stage_tile = [&](int buf, int kt2) {
    const unsigned short* kg = kg0 + (size_t)kt2 * KT * DHEAD;
#pragma unroll
    for (int c = 0; c < 2; ++c) {
      int call = wid * 2 + c;                 // 8 calls x 8 rows = 64 rows
      int r = call * 8 + srow;
      gl_lds16(kg + r * 64 + sblk * 8, &stage[buf][0][call * 512]);
      gl_lds16(vt0 + (size_t)r * SEQ + kt2 * KT + sblk * 8, &stage[buf][1][call * 512]);
    }
  };

  f32x4 oacc[2][4] = {};
  float lsum[2] = {0.f, 0.f};
  unsigned short* Pw = Pws[wid];

  stage_tile(0, 0);
  int buf = 0;
  for (int kt2 = 0; kt2 < NT; ++kt2) {
    __syncthreads();                          // staging(buf) complete
    if (kt2 + 1 < NT) stage_tile(buf ^ 1, kt2 + 1);  // overlap with compute
    const unsigned short* Ks = &stage[buf][0][0];
    const unsigned short* Vs = &stage[buf][1][0];

    // S^T = K Q^T  (lane: qrow = mi*16+ll, keys = ni*16 + quad*4 + r)
    f32x4 st[2][4] = {};
#pragma unroll
    for (int ks = 0; ks < 2; ++ks)
#pragma unroll
      for (int ni = 0; ni < 4; ++ni) {
        int r = ni * 16 + ll;
        int blk = (ks * 4 + quad) ^ (ll & 7);
        u16x8 kf = *(const u16x8*)&Ks[r * 64 + blk * 8];
        st[0][ni] = mfma16(kf, qf[0][ks], st[0][ni]);
        st[1][ni] = mfma16(kf, qf[1][ks], st[1][ni]);
      }

    // p = exp(s); per-lane partial row-sum; packed b64 P writes (row-major P)
#pragma unroll
    for (int mi = 0; mi < 2; ++mi)
#pragma unroll
      for (int ni = 0; ni < 4; ++ni) {
        float p0 = __expf(st[mi][ni][0]);
        float p1 = __expf(st[mi][ni][1]);
        float p2 = __expf(st[mi][ni][2]);
        float p3 = __expf(st[mi][ni][3]);
        lsum[mi] += (p0 + p1) + (p2 + p3);
        uint2 pk;
        pk.x = pk_bf16(p0, p1);
        pk.y = pk_bf16(p2, p3);
        *(uint2*)&Pw[(mi * 16 + ll) * 72 + ni * 16 + quad * 4] = pk;
      }
    asm volatile("s_waitcnt lgkmcnt(0)" ::: "memory");  // wave-local P RAW

    // O += P V   (P A-frag rows = qrow; Vt B-frag rows = d, swizzled)
#pragma unroll
    for (int ks = 0; ks < 2; ++ks) {
      u16x8 pf0 = *(const u16x8*)&Pw[(ll) * 72 + ks * 32 + quad * 8];
      u16x8 pf1 = *(const u16x8*)&Pw[(16 + ll) * 72 + ks * 32 + quad * 8];
#pragma unroll
      for (int di = 0; di < 4; ++di) {
        int r = di * 16 + ll;
        int blk = (ks * 4 + quad) ^ (ll & 7);
        u16x8 vf = *(const u16x8*)&Vs[r * 64 + blk * 8];
        oacc[0][di] = mfma16(pf0, vf, oacc[0][di]);
        oacc[1][di] = mfma16(pf1, vf, oacc[1][di]);
      }
    }
    buf ^= 1;
  }

  // cross-quad row-sum completion: lane (quad,ll) -> full sum for qrow=ll
  float lsF[2];
#pragma unroll
  for (int mi = 0; mi < 2; ++mi) {
    float ls = lsum[mi];
    ls += __shfl_xor(ls, 16);
    ls += __shfl_xor(ls, 32);
    lsF[mi] = ls;
  }

  // epilogue: O C-layout row = quad*4+r, col d = di*16+ll
  const int b = bh / NHEADS, h = bh - b * NHEADS;
#pragma unroll
  for (int mi = 0; mi < 2; ++mi) {
#pragma unroll
    for (int r = 0; r < 4; ++r) {
      float inv = 1.0f / __shfl(lsF[mi], quad * 4 + r);
      int row = qt * 128 + wid * 32 + mi * 16 + quad * 4 + r;
      size_t base = ((size_t)(b * SEQ + row)) * DMODEL + h * DHEAD;
#pragma unroll
      for (int di = 0; di < 4; ++di)
        ao[base + di * 16 + ll] = f2bf(oacc[mi][di][r] * inv);
    }
  }
}

// ---------------------------------------------------------------------------
// GEMM2: ao[8192][768] @ W_out (Bt) + b_out -> out fp32. BK=64, swizzled.
// ---------------------------------------------------------------------------
__global__ __launch_bounds__(256, 3) void gemm_out_kernel(
    const unsigned short* __restrict__ A, const unsigned short* __restrict__ Bt,
    const float* __restrict__ bias, float* __restrict__ out) {
  __shared__ alignas(16) unsigned short As[128 * 64];
  __shared__ alignas(16) unsigned short Bs[128 * 64];
  const int t = threadIdx.x, wid = t >> 6, l = t & 63, quad = l >> 4, ll = l & 15;
  const int m0 = blockIdx.x * 128, n0 = blockIdx.y * 128;
  const int wm = (wid >> 1) * 64, wn = (wid & 1) * 64;
  const int srow = l >> 3;
  const int sblk = (l & 7) ^ srow;
  f32x4 acc[4][4] = {};
  for (int k0 = 0; k0 < DMODEL; k0 += 64) {
#pragma unroll
    for (int cc = 0; cc < 4; ++cc) {
      int call = wid * 4 + cc;
      int r = call * 8 + srow;
      gl_lds16(A  + (size_t)(m0 + r) * DMODEL + k0 + sblk * 8, &As[call * 512]);
      gl_lds16(Bt + (size_t)(n0 + r) * DMODEL + k0 + sblk * 8, &Bs[call * 512]);
    }
    __syncthreads();
#pragma unroll
    for (int ks = 0; ks < 2; ++ks) {
      u16x8 af[4], bf[4];
#pragma unroll
      for (int i = 0; i < 4; ++i) {
        int ra = wm + i * 16 + ll, rb = wn + i * 16 + ll;
        int blk = (ks * 4 + quad) ^ (ll & 7);
        af[i] = *(const u16x8*)&As[ra * 64 + blk * 8];
        bf[i] = *(const u16x8*)&Bs[rb * 64 + blk * 8];
      }
#pragma unroll
      for (int mi = 0; mi < 4; ++mi)
#pragma unroll
        for (int ni = 0; ni < 4; ++ni)
          acc[mi][ni] = mfma16(af[mi], bf[ni], acc[mi][ni]);
    }
    __syncthreads();
  }
#pragma unroll
  for (int mi = 0; mi < 4; ++mi) {
#pragma unroll
    for (int ni = 0; ni < 4; ++ni) {
      int gm = m0 + wm + mi * 16 + quad * 4;
      int gn = n0 + wn + ni * 16 + ll;
      float bv = bias[gn];
#pragma unroll
      for (int r = 0; r < 4; ++r)
        out[(size_t)(gm + r) * DMODEL + gn] = acc[mi][ni][r] + bv;
    }
  }
}

// ---------------------------------------------------------------------------
// launch
// ---------------------------------------------------------------------------
extern "C" void kernel_launch(void* const* d_in, const int* in_sizes, int n_in,
                              void* d_out, int out_size, void* d_ws, size_t ws_size,
                              hipStream_t stream) {
  const float* x     = (const float*)d_in[0];
  const float* ln_g  = (const float*)d_in[1];
  const float* ln_b  = (const float*)d_in[2];
  const float* W_qkv = (const float*)d_in[3];
  const float* b_qkv = (const float*)d_in[4];
  const float* W_out = (const float*)d_in[5];
  const float* b_out = (const float*)d_in[6];
  float* out = (float*)d_out;

  char* ws = (char*)d_ws;
  unsigned short* xn    = (unsigned short*)(ws);               // 12,582,912 B
  unsigned short* wqkvt = (unsigned short*)(ws + 12582912);    //  3,538,944 B
  unsigned short* woutt = (unsigned short*)(ws + 16121856);    //  1,179,648 B
  unsigned short* qb    = (unsigned short*)(ws + 17301504);    // 12,582,912 B
  unsigned short* kb    = (unsigned short*)(ws + 29884416);    // 12,582,912 B
  unsigned short* vt    = (unsigned short*)(ws + 42467328);    // 12,582,912 B
  unsigned short* ao    = xn;  // xn dead after gemm_qkv

  ln_kernel<<<MROWS, 256, 0, stream>>>(x, ln_g, ln_b, xn);
  tconv_kernel<<<dim3(NQKV / 32, DMODEL / 32), 256, 0, stream>>>(W_qkv, wqkvt, NQKV);
  tconv_kernel<<<dim3(DMODEL / 32, DMODEL / 32), 256, 0, stream>>>(W_out, woutt, DMODEL);
  gemm_qkv_kernel<<<dim3(MROWS / 128, NQKV / 128), 256, 0, stream>>>(xn, wqkvt, b_qkv, qb, kb, vt);
  attn_kernel<<<dim3(SEQ / 128, NBATCH * NHEADS), 256, 0, stream>>>(qb, kb, vt, ao);
  gemm_out_kernel<<<dim3(MROWS / 128, DMODEL / 128), 256, 0, stream>>>(ao, woutt, b_out, out);
}

// Round 5
// 240.196 us; speedup vs baseline: 1.0178x; 1.0178x over previous
//
#include <hip/hip_runtime.h>
#include <cstdint>
#include <cstddef>

// ---------------------------------------------------------------------------
// Pre-LN multi-head attention block. B=4, N=2048, D=768, H=12, Dh=64.
// bf16 MFMA 16x16x32; fp32 in/out. XOR-swizzled LDS tiles.
// GEMM orientation chosen per-output so C-layout matches store layout
// (packed b64/b128 epilogues, no scalar store storms).
// ---------------------------------------------------------------------------

#define SEQ    2048
#define NBATCH 4
#define DMODEL 768
#define NHEADS 12
#define DHEAD  64
#define MROWS  (NBATCH * SEQ)   // 8192
#define NQKV   (3 * DMODEL)     // 2304
#define KT     64               // attention key-tile
#define NT     (SEQ / KT)       // 32

using f32x4  = __attribute__((ext_vector_type(4))) float;
using u16x8  = __attribute__((ext_vector_type(8))) unsigned short;
using s16x8  = __attribute__((ext_vector_type(8))) short;

__device__ __forceinline__ unsigned short f2bf(float f) {
  union { float f; unsigned int u; } x; x.f = f;
  unsigned int r = x.u + 0x7fffu + ((x.u >> 16) & 1u);   // RNE
  return (unsigned short)(r >> 16);
}

#if defined(__has_builtin)
#if __has_builtin(__builtin_amdgcn_cvt_pk_bf16_f32)
#define HAVE_PK_BF16 1
#endif
#if __has_builtin(__builtin_amdgcn_exp2f)
#define HAVE_EXP2 1
#endif
#endif

__device__ __forceinline__ unsigned int pk_bf16(float a, float b) {
#ifdef HAVE_PK_BF16
  auto v = __builtin_amdgcn_cvt_pk_bf16_f32(a, b);
  union { decltype(v) v2; unsigned int u; } c; c.v2 = v; return c.u;
#else
  return (unsigned int)f2bf(a) | ((unsigned int)f2bf(b) << 16);
#endif
}

// 2^x in one v_exp_f32 (q is pre-scaled by 0.125*log2(e))
__device__ __forceinline__ float fexp2(float x) {
#ifdef HAVE_EXP2
  return __builtin_amdgcn_exp2f(x);
#else
  return exp2f(x);
#endif
}

__device__ __forceinline__ f32x4 mfma16(u16x8 a, u16x8 b, f32x4 c) {
  return __builtin_amdgcn_mfma_f32_16x16x32_bf16((s16x8)a, (s16x8)b, c, 0, 0, 0);
}

// async global->LDS, 16B/lane; lane i writes LDS base + i*16
__device__ __forceinline__ void gl_lds16(const void* g, void* l) {
  __builtin_amdgcn_global_load_lds(
      (const __attribute__((address_space(1))) void*)g,
      (__attribute__((address_space(3))) void*)l, 16, 0, 0);
}

// ---------------------------------------------------------------------------
// LayerNorm: fp32 x[8192][768] -> bf16 xn[8192][768]
// ---------------------------------------------------------------------------
__global__ __launch_bounds__(256) void ln_kernel(
    const float* __restrict__ x, const float* __restrict__ g,
    const float* __restrict__ bb, unsigned short* __restrict__ xn) {
  __shared__ float red[8];
  const int row = blockIdx.x, t = threadIdx.x;
  const float* xr = x + (size_t)row * DMODEL;
  float v0 = xr[t], v1 = xr[t + 256], v2 = xr[t + 512];
  float s = v0 + v1 + v2;
#pragma unroll
  for (int o = 32; o; o >>= 1) s += __shfl_down(s, o);
  if ((t & 63) == 0) red[t >> 6] = s;
  __syncthreads();
  float mu = (red[0] + red[1] + red[2] + red[3]) * (1.0f / DMODEL);
  float d0 = v0 - mu, d1 = v1 - mu, d2 = v2 - mu;
  float q = d0 * d0 + d1 * d1 + d2 * d2;
#pragma unroll
  for (int o = 32; o; o >>= 1) q += __shfl_down(q, o);
  if ((t & 63) == 0) red[4 + (t >> 6)] = q;
  __syncthreads();
  float var = (red[4] + red[5] + red[6] + red[7]) * (1.0f / DMODEL);
  float rstd = rsqrtf(var + 1e-5f);
  size_t base = (size_t)row * DMODEL;
  xn[base + t]       = f2bf(d0 * rstd * g[t]       + bb[t]);
  xn[base + t + 256] = f2bf(d1 * rstd * g[t + 256] + bb[t + 256]);
  xn[base + t + 512] = f2bf(d2 * rstd * g[t + 512] + bb[t + 512]);
}

// ---------------------------------------------------------------------------
// Transpose + fp32->bf16: W[K=768][N] -> Wt[N][768]
// ---------------------------------------------------------------------------
__global__ __launch_bounds__(256) void tconv_kernel(
    const float* __restrict__ W, unsigned short* __restrict__ Wt, int N) {
  __shared__ float tile[32][33];
  const int n0 = blockIdx.x * 32, k0 = blockIdx.y * 32;
  const int tx = threadIdx.x & 31, ty = threadIdx.x >> 5;
#pragma unroll
  for (int r = 0; r < 4; ++r)
    tile[ty + r * 8][tx] = W[(size_t)(k0 + ty + r * 8) * N + n0 + tx];
  __syncthreads();
#pragma unroll
  for (int r = 0; r < 4; ++r)
    Wt[(size_t)(n0 + ty + r * 8) * DMODEL + k0 + tx] = f2bf(tile[tx][ty + r * 8]);
}

// ---------------------------------------------------------------------------
// GEMM-QK (swapped orientation): C^T[n_qkv][seq] = Wt_rows · xn_rows^T.
// Lane holds 4 consecutive d for one seq -> packed b64 stores.
// q rows [0,768) scaled by 0.125*log2(e) (exp2 in attn); k rows [768,1536).
// grid (12, 64), block 256.
// ---------------------------------------------------------------------------
__global__ __launch_bounds__(256, 2) void gemm_qk_kernel(
    const unsigned short* __restrict__ Wt, const unsigned short* __restrict__ xn,
    const float* __restrict__ bias, unsigned short* __restrict__ qb,
    unsigned short* __restrict__ kb) {
  __shared__ alignas(16) unsigned short As[128 * 64];
  __shared__ alignas(16) unsigned short Bs[128 * 64];
  const int t = threadIdx.x, wid = t >> 6, l = t & 63, quad = l >> 4, ll = l & 15;
  const int a0 = blockIdx.x * 128;   // n_qkv base in [0,1536)
  const int b0 = blockIdx.y * 128;   // seq base
  const int wa = (wid >> 1) * 64, wb = (wid & 1) * 64;
  const int srow = l >> 3, sblk = (l & 7) ^ srow;
  f32x4 acc[4][4] = {};
  for (int k0 = 0; k0 < DMODEL; k0 += 64) {
#pragma unroll
    for (int cc = 0; cc < 4; ++cc) {
      int call = wid * 4 + cc;
      int r = call * 8 + srow;
      gl_lds16(Wt + (size_t)(a0 + r) * DMODEL + k0 + sblk * 8, &As[call * 512]);
      gl_lds16(xn + (size_t)(b0 + r) * DMODEL + k0 + sblk * 8, &Bs[call * 512]);
    }
    __syncthreads();
#pragma unroll
    for (int ks = 0; ks < 2; ++ks) {
      u16x8 af[4], bf[4];
#pragma unroll
      for (int i = 0; i < 4; ++i) {
        int ra = wa + i * 16 + ll, rb = wb + i * 16 + ll;
        int blk = (ks * 4 + quad) ^ (ll & 7);
        af[i] = *(const u16x8*)&As[ra * 64 + blk * 8];
        bf[i] = *(const u16x8*)&Bs[rb * 64 + blk * 8];
      }
#pragma unroll
      for (int mi = 0; mi < 4; ++mi)
#pragma unroll
        for (int ni = 0; ni < 4; ++ni)
          acc[mi][ni] = mfma16(af[mi], bf[ni], acc[mi][ni]);
    }
    __syncthreads();
  }
  const bool isq = (a0 < DMODEL);
  unsigned short* dst = isq ? qb : kb;
  const float sc = isq ? 0.18033688f : 1.0f;   // q: 0.125 * log2(e)
#pragma unroll
  for (int mi = 0; mi < 4; ++mi) {
    int row0 = a0 + wa + mi * 16 + quad * 4;   // n_qkv (4 consecutive via r)
    float4 bv = *(const float4*)&bias[row0];
    int rr = isq ? row0 : row0 - DMODEL;
    int h = rr >> 6, d0 = rr & 63;
#pragma unroll
    for (int ni = 0; ni < 4; ++ni) {
      int seq = b0 + wb + ni * 16 + ll;
      int b = seq >> 11, i = seq & 2047;
      uint2 pk;
      pk.x = pk_bf16((acc[mi][ni][0] + bv.x) * sc, (acc[mi][ni][1] + bv.y) * sc);
      pk.y = pk_bf16((acc[mi][ni][2] + bv.z) * sc, (acc[mi][ni][3] + bv.w) * sc);
      *(uint2*)&dst[(size_t)((b * NHEADS + h) * SEQ + i) * DHEAD + d0] = pk;
    }
  }
}

// ---------------------------------------------------------------------------
// GEMM-V (original orientation): xn @ W_qkv cols [1536,2304) -> vt [bh][d][SEQ]
// Lane holds 4 consecutive seq for one d -> packed b64 stores into vt.
// grid (64, 6), block 256.
// ---------------------------------------------------------------------------
__global__ __launch_bounds__(256, 2) void gemm_v_kernel(
    const unsigned short* __restrict__ A, const unsigned short* __restrict__ Bt,
    const float* __restrict__ bias, unsigned short* __restrict__ vt) {
  __shared__ alignas(16) unsigned short As[128 * 64];
  __shared__ alignas(16) unsigned short Bs[128 * 64];
  const int t = threadIdx.x, wid = t >> 6, l = t & 63, quad = l >> 4, ll = l & 15;
  const int m0 = blockIdx.x * 128;
  const int n0 = 2 * DMODEL + blockIdx.y * 128;   // [1536, 2304)
  const int wm = (wid >> 1) * 64, wn = (wid & 1) * 64;
  const int srow = l >> 3, sblk = (l & 7) ^ srow;
  f32x4 acc[4][4] = {};
  for (int k0 = 0; k0 < DMODEL; k0 += 64) {
#pragma unroll
    for (int cc = 0; cc < 4; ++cc) {
      int call = wid * 4 + cc;
      int r = call * 8 + srow;
      gl_lds16(A  + (size_t)(m0 + r) * DMODEL + k0 + sblk * 8, &As[call * 512]);
      gl_lds16(Bt + (size_t)(n0 + r) * DMODEL + k0 + sblk * 8, &Bs[call * 512]);
    }
    __syncthreads();
#pragma unroll
    for (int ks = 0; ks < 2; ++ks) {
      u16x8 af[4], bf[4];
#pragma unroll
      for (int i = 0; i < 4; ++i) {
        int ra = wm + i * 16 + ll, rb = wn + i * 16 + ll;
        int blk = (ks * 4 + quad) ^ (ll & 7);
        af[i] = *(const u16x8*)&As[ra * 64 + blk * 8];
        bf[i] = *(const u16x8*)&Bs[rb * 64 + blk * 8];
      }
#pragma unroll
      for (int mi = 0; mi < 4; ++mi)
#pragma unroll
        for (int ni = 0; ni < 4; ++ni)
          acc[mi][ni] = mfma16(af[mi], bf[ni], acc[mi][ni]);
    }
    __syncthreads();
  }
#pragma unroll
  for (int mi = 0; mi < 4; ++mi) {
    int gm = m0 + wm + mi * 16 + quad * 4;
    int b = gm >> 11, i0 = gm & 2047;
#pragma unroll
    for (int ni = 0; ni < 4; ++ni) {
      int gn = n0 + wn + ni * 16 + ll;
      float bv = bias[gn];
      int rem = gn - 2 * DMODEL;
      int h = rem >> 6, d = rem & 63;
      int bh = b * NHEADS + h;
      uint2 pk;
      pk.x = pk_bf16(acc[mi][ni][0] + bv, acc[mi][ni][1] + bv);
      pk.y = pk_bf16(acc[mi][ni][2] + bv, acc[mi][ni][3] + bv);
      *(uint2*)&vt[((size_t)bh * DHEAD + d) * SEQ + i0] = pk;
    }
  }
}

// ---------------------------------------------------------------------------
// Flash attention, streaming sum-of-exp2 (q pre-scaled by 0.125*log2e).
// grid (16 q-tiles, 48 bh), block 256 (4 waves x 32 q-rows).
// S^T = K·Q^T: lane holds qrow=ll, keys quad*4+r -> packed b64 P writes.
// K-tile 64, double-buffered DMA staging, one barrier/iter, swizzled tiles.
// ---------------------------------------------------------------------------
__global__ __launch_bounds__(256, 3) void attn_kernel(
    const unsigned short* __restrict__ qbuf, const unsigned short* __restrict__ kbuf,
    const unsigned short* __restrict__ vtg, unsigned short* __restrict__ ao) {
  __shared__ alignas(16) unsigned short stage[2][2][KT * DHEAD]; // [buf][K,Vt]
  __shared__ alignas(16) unsigned short Pws[4][32 * 72];
  const int t = threadIdx.x, wid = t >> 6, l = t & 63, quad = l >> 4, ll = l & 15;
  const int qt = blockIdx.x, bh = blockIdx.y;
  const unsigned short* qg  = qbuf + ((size_t)bh * SEQ + qt * 128) * DHEAD;
  const unsigned short* kg0 = kbuf + (size_t)bh * SEQ * DHEAD;
  const unsigned short* vt0 = vtg  + (size_t)bh * DHEAD * SEQ;
  const int srow = l >> 3;                    // 0..7
  const int sblk = (l & 7) ^ srow;            // swizzled source block

  // stage Q (16KB over stage[0], swizzled), hoist fragments, free region
  unsigned short* Qs = &stage[0][0][0];
#pragma unroll
  for (int cc = 0; cc < 4; ++cc) {
    int call = wid * 4 + cc;                  // 16 calls x 8 rows = 128 rows
    gl_lds16(qg + (call * 8 + srow) * 64 + sblk * 8, Qs + call * 512);
  }
  __syncthreads();
  u16x8 qf[2][2];
#pragma unroll
  for (int mi = 0; mi < 2; ++mi)
#pragma unroll
    for (int ks = 0; ks < 2; ++ks) {
      int r = wid * 32 + mi * 16 + ll;
      int blk = (ks * 4 + quad) ^ (ll & 7);
      qf[mi][ks] = *(const u16x8*)&Qs[r * 64 + blk * 8];
    }
  __syncthreads();

  auto stage_tile = [&](int buf, int kt2) {
    const unsigned short* kg = kg0 + (size_t)kt2 * KT * DHEAD;
#pragma unroll
    for (int c = 0; c < 2; ++c) {
      int call = wid * 2 + c;                 // 8 calls x 8 rows = 64 rows
      int r = call * 8 + srow;
      gl_lds16(kg + r * 64 + sblk * 8, &stage[buf][0][call * 512]);
      gl_lds16(vt0 + (size_t)r * SEQ + kt2 * KT + sblk * 8, &stage[buf][1][call * 512]);
    }
  };

  f32x4 oacc[2][4] = {};
  float lsum[2] = {0.f, 0.f};
  unsigned short* Pw = Pws[wid];

  stage_tile(0, 0);
  int buf = 0;
  for (int kt2 = 0; kt2 < NT; ++kt2) {
    __syncthreads();                          // staging(buf) complete
    if (kt2 + 1 < NT) stage_tile(buf ^ 1, kt2 + 1);  // overlap with compute
    const unsigned short* Ks = &stage[buf][0][0];
    const unsigned short* Vs = &stage[buf][1][0];

    // S^T = K Q^T  (lane: qrow = mi*16+ll, keys = ni*16 + quad*4 + r)
    f32x4 st[2][4] = {};
#pragma unroll
    for (int ks = 0; ks < 2; ++ks)
#pragma unroll
      for (int ni = 0; ni < 4; ++ni) {
        int r = ni * 16 + ll;
        int blk = (ks * 4 + quad) ^ (ll & 7);
        u16x8 kf = *(const u16x8*)&Ks[r * 64 + blk * 8];
        st[0][ni] = mfma16(kf, qf[0][ks], st[0][ni]);
        st[1][ni] = mfma16(kf, qf[1][ks], st[1][ni]);
      }

    // p = 2^s; per-lane partial row-sum; packed b64 P writes (row-major P)
#pragma unroll
    for (int mi = 0; mi < 2; ++mi)
#pragma unroll
      for (int ni = 0; ni < 4; ++ni) {
        float p0 = fexp2(st[mi][ni][0]);
        float p1 = fexp2(st[mi][ni][1]);
        float p2 = fexp2(st[mi][ni][2]);
        float p3 = fexp2(st[mi][ni][3]);
        lsum[mi] += (p0 + p1) + (p2 + p3);
        uint2 pk;
        pk.x = pk_bf16(p0, p1);
        pk.y = pk_bf16(p2, p3);
        *(uint2*)&Pw[(mi * 16 + ll) * 72 + ni * 16 + quad * 4] = pk;
      }
    asm volatile("s_waitcnt lgkmcnt(0)" ::: "memory");  // wave-local P RAW

    // O += P V   (P A-frag rows = qrow; Vt B-frag rows = d, swizzled)
#pragma unroll
    for (int ks = 0; ks < 2; ++ks) {
      u16x8 pf0 = *(const u16x8*)&Pw[(ll) * 72 + ks * 32 + quad * 8];
      u16x8 pf1 = *(const u16x8*)&Pw[(16 + ll) * 72 + ks * 32 + quad * 8];
#pragma unroll
      for (int di = 0; di < 4; ++di) {
        int r = di * 16 + ll;
        int blk = (ks * 4 + quad) ^ (ll & 7);
        u16x8 vf = *(const u16x8*)&Vs[r * 64 + blk * 8];
        oacc[0][di] = mfma16(pf0, vf, oacc[0][di]);
        oacc[1][di] = mfma16(pf1, vf, oacc[1][di]);
      }
    }
    buf ^= 1;
  }

  // cross-quad row-sum completion: lane (quad,ll) -> full sum for qrow=ll
  float lsF[2];
#pragma unroll
  for (int mi = 0; mi < 2; ++mi) {
    float ls = lsum[mi];
    ls += __shfl_xor(ls, 16);
    ls += __shfl_xor(ls, 32);
    lsF[mi] = ls;
  }

  // epilogue: O C-layout row = quad*4+r, col d = di*16+ll
  const int b = bh / NHEADS, h = bh - b * NHEADS;
#pragma unroll
  for (int mi = 0; mi < 2; ++mi) {
#pragma unroll
    for (int r = 0; r < 4; ++r) {
      float inv = 1.0f / __shfl(lsF[mi], quad * 4 + r);
      int row = qt * 128 + wid * 32 + mi * 16 + quad * 4 + r;
      size_t base = ((size_t)(b * SEQ + row)) * DMODEL + h * DHEAD;
#pragma unroll
      for (int di = 0; di < 4; ++di)
        ao[base + di * 16 + ll] = f2bf(oacc[mi][di][r] * inv);
    }
  }
}

// ---------------------------------------------------------------------------
// GEMM-OUT (swapped orientation): C^T[n_out][seq] = Woutt_rows · ao_rows^T.
// Lane holds 4 consecutive n_out for one seq -> packed float4 stores.
// grid (6, 64), block 256.
// ---------------------------------------------------------------------------
__global__ __launch_bounds__(256, 2) void gemm_out_kernel(
    const unsigned short* __restrict__ Wt, const unsigned short* __restrict__ ao,
    const float* __restrict__ bias, float* __restrict__ out) {
  __shared__ alignas(16) unsigned short As[128 * 64];
  __shared__ alignas(16) unsigned short Bs[128 * 64];
  const int t = threadIdx.x, wid = t >> 6, l = t & 63, quad = l >> 4, ll = l & 15;
  const int a0 = blockIdx.x * 128;   // n_out base
  const int b0 = blockIdx.y * 128;   // seq base
  const int wa = (wid >> 1) * 64, wb = (wid & 1) * 64;
  const int srow = l >> 3, sblk = (l & 7) ^ srow;
  f32x4 acc[4][4] = {};
  for (int k0 = 0; k0 < DMODEL; k0 += 64) {
#pragma unroll
    for (int cc = 0; cc < 4; ++cc) {
      int call = wid * 4 + cc;
      int r = call * 8 + srow;
      gl_lds16(Wt + (size_t)(a0 + r) * DMODEL + k0 + sblk * 8, &As[call * 512]);
      gl_lds16(ao + (size_t)(b0 + r) * DMODEL + k0 + sblk * 8, &Bs[call * 512]);
    }
    __syncthreads();
#pragma unroll
    for (int ks = 0; ks < 2; ++ks) {
      u16x8 af[4], bf[4];
#pragma unroll
      for (int i = 0; i < 4; ++i) {
        int ra = wa + i * 16 + ll, rb = wb + i * 16 + ll;
        int blk = (ks * 4 + quad) ^ (ll & 7);
        af[i] = *(const u16x8*)&As[ra * 64 + blk * 8];
        bf[i] = *(const u16x8*)&Bs[rb * 64 + blk * 8];
      }
#pragma unroll
      for (int mi = 0; mi < 4; ++mi)
#pragma unroll
        for (int ni = 0; ni < 4; ++ni)
          acc[mi][ni] = mfma16(af[mi], bf[ni], acc[mi][ni]);
    }
    __syncthreads();
  }
#pragma unroll
  for (int mi = 0; mi < 4; ++mi) {
    int row0 = a0 + wa + mi * 16 + quad * 4;   // n_out, 4 consecutive via r
    float4 bv = *(const float4*)&bias[row0];
#pragma unroll
    for (int ni = 0; ni < 4; ++ni) {
      int seq = b0 + wb + ni * 16 + ll;
      float4 o;
      o.x = acc[mi][ni][0] + bv.x;
      o.y = acc[mi][ni][1] + bv.y;
      o.z = acc[mi][ni][2] + bv.z;
      o.w = acc[mi][ni][3] + bv.w;
      *(float4*)&out[(size_t)seq * DMODEL + row0] = o;
    }
  }
}

// ---------------------------------------------------------------------------
// launch
// ---------------------------------------------------------------------------
extern "C" void kernel_launch(void* const* d_in, const int* in_sizes, int n_in,
                              void* d_out, int out_size, void* d_ws, size_t ws_size,
                              hipStream_t stream) {
  const float* x     = (const float*)d_in[0];
  const float* ln_g  = (const float*)d_in[1];
  const float* ln_b  = (const float*)d_in[2];
  const float* W_qkv = (const float*)d_in[3];
  const float* b_qkv = (const float*)d_in[4];
  const float* W_out = (const float*)d_in[5];
  const float* b_out = (const float*)d_in[6];
  float* out = (float*)d_out;

  char* ws = (char*)d_ws;
  unsigned short* xn    = (unsigned short*)(ws);               // 12,582,912 B
  unsigned short* wqkvt = (unsigned short*)(ws + 12582912);    //  3,538,944 B
  unsigned short* woutt = (unsigned short*)(ws + 16121856);    //  1,179,648 B
  unsigned short* qb    = (unsigned short*)(ws + 17301504);    // 12,582,912 B
  unsigned short* kb    = (unsigned short*)(ws + 29884416);    // 12,582,912 B
  unsigned short* vt    = (unsigned short*)(ws + 42467328);    // 12,582,912 B
  unsigned short* ao    = xn;  // xn dead after the QKV GEMMs

  ln_kernel<<<MROWS, 256, 0, stream>>>(x, ln_g, ln_b, xn);
  tconv_kernel<<<dim3(NQKV / 32, DMODEL / 32), 256, 0, stream>>>(W_qkv, wqkvt, NQKV);
  tconv_kernel<<<dim3(DMODEL / 32, DMODEL / 32), 256, 0, stream>>>(W_out, woutt, DMODEL);
  gemm_qk_kernel<<<dim3(12, 64), 256, 0, stream>>>(wqkvt, xn, b_qkv, qb, kb);
  gemm_v_kernel<<<dim3(64, 6), 256, 0, stream>>>(xn, wqkvt, b_qkv, vt);
  attn_kernel<<<dim3(SEQ / 128, NBATCH * NHEADS), 256, 0, stream>>>(qb, kb, vt, ao);
  gemm_out_kernel<<<dim3(6, 64), 256, 0, stream>>>(woutt, ao, b_out, out);
}